// Round 5
// baseline (506.445 us; speedup 1.0000x reference)
//
#include <hip/hip_runtime.h>

#define N_NODES 20000
#define DEG 16
#define GRAPHS 16
#define NPG 1250

typedef __bf16 bf16x8 __attribute__((ext_vector_type(8)));
typedef float f32x4 __attribute__((ext_vector_type(4)));
#define MFMA16(a, b, c) __builtin_amdgcn_mfma_f32_16x16x32_bf16(a, b, c, 0, 0, 0)

// ---- workspace layout (bf16 element offsets) ----
#define OFF_X1    0            // x1 [20000][128] bf16
#define OFF_P1    2560000      // c1W1 packed: MT=8  KT=1 -> 4096
#define OFF_P2    2564096      // c1W2 packed: MT=8  KT=4 -> 16384
#define OFF_P3    2580480      // c2W1 packed: MT=16 KT=5 -> 40960
#define OFF_P4    2621440      // c2W2 packed: MT=16 KT=8 -> 65536
#define OFF_POOL_BYTES 5373952 // pooled u32[16*256]

// Frag layout (A-role == B-role for mfma_f32_16x16x32_bf16):
//   frag[((t*KT+kt)*64+lane)*8 + j] = X[k = kt*32 + (lane>>4)*8 + j][idx = lane&15]
__global__ __launch_bounds__(256) void pack_weights(
    const float* __restrict__ c1W1, const float* __restrict__ c1W2,
    const float* __restrict__ c2W1, const float* __restrict__ c2W2,
    __bf16* __restrict__ p1, __bf16* __restrict__ p2,
    __bf16* __restrict__ p3, __bf16* __restrict__ p4,
    unsigned int* __restrict__ pooled)
{
    int t = blockIdx.x * 256 + threadIdx.x;
    if (t < GRAPHS * 256) pooled[t] = 0u;   // flipped(-inf) == 0
    if (t >= 15872) return;
    const float* W; __bf16* out; int M, Kreal, KT, grp;
    if      (t <  512)  { W = c1W1; out = p1; M = 128; Kreal =   6; KT = 1; grp = t; }
    else if (t < 2560)  { W = c1W2; out = p2; M = 128; Kreal = 128; KT = 4; grp = t - 512; }
    else if (t < 7680)  { W = c2W1; out = p3; M = 256; Kreal = 131; KT = 5; grp = t - 2560; }
    else                { W = c2W2; out = p4; M = 256; Kreal = 256; KT = 8; grp = t - 7680; }
    int lane = grp & 63, rest = grp >> 6;
    int kt = rest % KT, mt = rest / KT;
    int m = mt * 16 + (lane & 15);
    int kbase = kt * 32 + ((lane >> 4) << 3);
    bf16x8 v;
    #pragma unroll
    for (int j = 0; j < 8; j++) {
        int k = kbase + j;
        v[j] = (k < Kreal) ? (__bf16)W[k * M + m] : (__bf16)0.f;
    }
    *(bf16x8*)&out[grp * 8] = v;
}

// =================== conv1 ===================
// 2500 blocks x 8 nodes, 4 blocks/CU. msg B-frags gathered straight to registers
// (quad-0 lanes carry k=0..5, rest zero). ONE barrier per block.
#define NB1 8
__global__ __launch_bounds__(256, 4) void conv1_kernel(
    const float* __restrict__ pos, const int* __restrict__ esrc,
    const __bf16* __restrict__ W1p, const float* __restrict__ b1,
    const __bf16* __restrict__ W2p, const float* __restrict__ b2,
    __bf16* __restrict__ x1)
{
    __shared__ __attribute__((aligned(16))) __bf16 hidF[NB1 * 4 * 64 * 8];  // 32 KB
    const int tid = threadIdx.x, lane = tid & 63, wave = tid >> 6;
    const int quad = lane >> 4, col = lane & 15;
    const int node0 = blockIdx.x * NB1;

    bf16x8 A1[2], B2w[2][4];
    f32x4 bias1[2];
    float b2v[2];
    #pragma unroll
    for (int i = 0; i < 2; i++) {
        int mtg = wave * 2 + i;
        A1[i] = *(const bf16x8*)&W1p[(mtg * 64 + lane) * 8];
        bias1[i] = *(const f32x4*)&b1[mtg * 16 + quad * 4];
        #pragma unroll
        for (int kt = 0; kt < 4; kt++)
            B2w[i][kt] = *(const bf16x8*)&W2p[((mtg * 4 + kt) * 64 + lane) * 8];
        b2v[i] = b2[mtg * 16 + col];
    }

    // ---- phase 1: gather msg to regs, MFMA, write hid frags ----
    #pragma unroll
    for (int nl = 0; nl < NB1; nl++) {
        bf16x8 B;
        #pragma unroll
        for (int j = 0; j < 8; j++) B[j] = (__bf16)0.f;
        if (quad == 0) {
            int d = node0 + nl;
            int s = esrc[d * 16 + col];
            float sx = pos[3*s], sy = pos[3*s+1], sz = pos[3*s+2];
            B[0] = (__bf16)sx; B[1] = (__bf16)sy; B[2] = (__bf16)sz;
            B[3] = (__bf16)(sx - pos[3*d]);
            B[4] = (__bf16)(sy - pos[3*d+1]);
            B[5] = (__bf16)(sz - pos[3*d+2]);
        }
        #pragma unroll
        for (int i = 0; i < 2; i++) {
            int mtg = wave * 2 + i;
            f32x4 acc = bias1[i];
            acc = MFMA16(A1[i], B, acc);
            union { __bf16 h[4]; uint2 u; } pk;
            #pragma unroll
            for (int r = 0; r < 4; r++) pk.h[r] = (__bf16)fmaxf(acc[r], 0.f);
            int kt2 = mtg >> 1;
            int lane2 = ((mtg * 2 + (quad >> 1)) & 3) * 16 + col;
            int j0 = (quad & 1) * 4;
            *(uint2*)&hidF[((nl * 4 + kt2) * 64 + lane2) * 8 + j0] = pk.u;
        }
    }
    __syncthreads();

    // ---- phase 2: D[edge][ch], edge-max, write x1 ----
    #pragma unroll
    for (int nl = 0; nl < NB1; nl++) {
        bf16x8 hA[4];
        #pragma unroll
        for (int kt = 0; kt < 4; kt++)
            hA[kt] = *(const bf16x8*)&hidF[((nl * 4 + kt) * 64 + lane) * 8];
        f32x4 acc[2];
        f32x4 z = {0.f, 0.f, 0.f, 0.f};
        acc[0] = z; acc[1] = z;
        #pragma unroll
        for (int kt = 0; kt < 4; kt++) {
            #pragma unroll
            for (int i = 0; i < 2; i++) acc[i] = MFMA16(hA[kt], B2w[i][kt], acc[i]);
        }
        #pragma unroll
        for (int i = 0; i < 2; i++) {
            int mtg = wave * 2 + i;
            float m = fmaxf(fmaxf(acc[i][0], acc[i][1]), fmaxf(acc[i][2], acc[i][3]));
            m = fmaxf(m, __shfl_xor(m, 16));
            m = fmaxf(m, __shfl_xor(m, 32));
            if (lane < 16)
                x1[(size_t)(node0 + nl) * 128 + mtg * 16 + lane] = (__bf16)(m + b2v[i]);
        }
    }
}

// =================== conv2 ===================
// 500 blocks x 512 threads x 40 nodes (20 tiles of NB2=2) -> 2 blocks/CU,
// 4 waves/SIMD (VGPR<=128). Producer waves 0-3: stage msg frags to LDS once
// (shared by all 4), layer1 -> hidF. Consumer waves 4-7: W2 register-resident,
// layer2 + fused global max-pool. Double-buffered, 1 barrier/tile.
#define NB2 2
#define NT2 20
__global__ __launch_bounds__(512, 4) void conv2_kernel(
    const float* __restrict__ pos, const int* __restrict__ esrc,
    const __bf16* __restrict__ x1,
    const __bf16* __restrict__ W1p, const float* __restrict__ b1,
    const __bf16* __restrict__ W2p, const float* __restrict__ b2,
    unsigned int* __restrict__ pooled)
{
    __shared__ __attribute__((aligned(16))) __bf16 msgF[2][NB2 * 5 * 64 * 8];  // 2x10 KB
    __shared__ __attribute__((aligned(16))) __bf16 hidF[2][NB2 * 8 * 64 * 8];  // 2x16 KB
    const int tid = threadIdx.x, lane = tid & 63, wave = tid >> 6;
    const int quad = lane >> 4, col = lane & 15;
    const int base = blockIdx.x * (NB2 * NT2);

    if (wave < 4) {
        // ===== producer: layer 1 =====
        bf16x8 A1[4][5];
        f32x4 bias1[4];
        #pragma unroll
        for (int i = 0; i < 4; i++) {
            int mtg = wave * 4 + i;
            #pragma unroll
            for (int kt = 0; kt < 5; kt++)
                A1[i][kt] = *(const bf16x8*)&W1p[((mtg * 5 + kt) * 64 + lane) * 8];
            bias1[i] = *(const f32x4*)&b1[mtg * 16 + quad * 4];
        }

        auto stage = [&](int n0, int buf) {
            #pragma unroll
            for (int s = 0; s < 3; s++) {
                int u = tid + 256 * s;
                if (u < NB2 * 5 * 64) {
                    int nl = u / 320, rr = u % 320;
                    int kt = rr >> 6, l = rr & 63;
                    int q = l >> 4, c = l & 15;
                    int d = n0 + nl;
                    if (kt < 4) {
                        int src = esrc[d * 16 + c];
                        *(uint4*)&msgF[buf][((nl * 5 + kt) * 64 + l) * 8] =
                            *(const uint4*)&x1[(size_t)src * 128 + kt * 32 + q * 8];
                    } else {
                        bf16x8 v;
                        #pragma unroll
                        for (int j = 0; j < 8; j++) v[j] = (__bf16)0.f;
                        if (q == 0) {
                            int src = esrc[d * 16 + c];
                            v[0] = (__bf16)(pos[3*src]   - pos[3*d]);
                            v[1] = (__bf16)(pos[3*src+1] - pos[3*d+1]);
                            v[2] = (__bf16)(pos[3*src+2] - pos[3*d+2]);
                        }
                        *(bf16x8*)&msgF[buf][((nl * 5 + kt) * 64 + l) * 8] = v;
                    }
                }
            }
        };

        stage(base, 0);
        __syncthreads();

        for (int k = 0; k < NT2; k++) {
            const int buf = k & 1;
            if (k + 1 < NT2) stage(base + (k + 1) * NB2, buf ^ 1);
            // compute layer1 for tile k from msgF[buf] -> hidF[buf]
            #pragma unroll
            for (int nl = 0; nl < NB2; nl++) {
                bf16x8 B[5];
                #pragma unroll
                for (int kt = 0; kt < 5; kt++)
                    B[kt] = *(const bf16x8*)&msgF[buf][((nl * 5 + kt) * 64 + lane) * 8];
                #pragma unroll
                for (int i = 0; i < 4; i++) {
                    int mtg = wave * 4 + i;
                    f32x4 acc = bias1[i];
                    #pragma unroll
                    for (int kt = 0; kt < 5; kt++) acc = MFMA16(A1[i][kt], B[kt], acc);
                    union { __bf16 h[4]; uint2 u; } pk;
                    #pragma unroll
                    for (int r = 0; r < 4; r++) pk.h[r] = (__bf16)fmaxf(acc[r], 0.f);
                    int kt2 = mtg >> 1;
                    int lane2 = ((mtg * 2 + (quad >> 1)) & 3) * 16 + col;
                    int j0 = (quad & 1) * 4;
                    *(uint2*)&hidF[buf][((nl * 8 + kt2) * 64 + lane2) * 8 + j0] = pk.u;
                }
            }
            __syncthreads();
        }
    } else {
        // ===== consumer: layer 2 + fused global max-pool =====
        const int wv = wave - 4;
        bf16x8 A2[4][8];
        #pragma unroll
        for (int i = 0; i < 4; i++) {
            int mtg = wv * 4 + i;
            #pragma unroll
            for (int kt = 0; kt < 8; kt++)
                A2[i][kt] = *(const bf16x8*)&W2p[((mtg * 8 + kt) * 64 + lane) * 8];
        }
        f32x4 runmax[4];
        #pragma unroll
        for (int i = 0; i < 4; i++)
            #pragma unroll
            for (int r = 0; r < 4; r++) runmax[i][r] = -3.4e38f;

        auto flushfn = [&](int g) {
            #pragma unroll
            for (int i = 0; i < 4; i++) {
                #pragma unroll
                for (int r = 0; r < 4; r++) {
                    float v = runmax[i][r];
                    v = fmaxf(v, __shfl_xor(v, 1));
                    v = fmaxf(v, __shfl_xor(v, 2));
                    v = fmaxf(v, __shfl_xor(v, 4));
                    v = fmaxf(v, __shfl_xor(v, 8));
                    if (col == 0) {
                        int c = (wv * 4 + i) * 16 + quad * 4 + r;
                        float val = v + b2[c];
                        unsigned u = __float_as_uint(val);
                        u = (u & 0x80000000u) ? ~u : (u | 0x80000000u);
                        atomicMax(&pooled[g * 256 + c], u);
                    }
                }
            }
        };
        auto consume = [&](int tk) {
            int buf1 = tk & 1;
            #pragma unroll
            for (int nl = 0; nl < NB2; nl++) {
                bf16x8 hB[8];
                #pragma unroll
                for (int kt = 0; kt < 8; kt++)
                    hB[kt] = *(const bf16x8*)&hidF[buf1][((nl * 8 + kt) * 64 + lane) * 8];
                f32x4 acc[4];
                f32x4 z = {0.f, 0.f, 0.f, 0.f};
                #pragma unroll
                for (int i = 0; i < 4; i++) acc[i] = z;
                #pragma unroll
                for (int kt = 0; kt < 8; kt++) {
                    #pragma unroll
                    for (int i = 0; i < 4; i++) acc[i] = MFMA16(A2[i][kt], hB[kt], acc[i]);
                }
                #pragma unroll
                for (int i = 0; i < 4; i++)
                    #pragma unroll
                    for (int r = 0; r < 4; r++)
                        runmax[i][r] = fmaxf(runmax[i][r], acc[i][r]);
            }
        };

        __syncthreads();   // matches producer's post-stage-0 barrier
        int gprev = base / NPG;
        for (int k = 0; k < NT2; k++) {
            if (k > 0) {
                int n0 = base + (k - 1) * NB2;
                int g = n0 / NPG;
                if (g != gprev) {
                    flushfn(gprev);
                    #pragma unroll
                    for (int i = 0; i < 4; i++)
                        #pragma unroll
                        for (int r = 0; r < 4; r++) runmax[i][r] = -3.4e38f;
                    gprev = g;
                }
                consume(k - 1);
            }
            __syncthreads();
        }
        {   // final tile
            int n0 = base + (NT2 - 1) * NB2;
            int g = n0 / NPG;
            if (g != gprev) {
                flushfn(gprev);
                #pragma unroll
                for (int i = 0; i < 4; i++)
                    #pragma unroll
                    for (int r = 0; r < 4; r++) runmax[i][r] = -3.4e38f;
                gprev = g;
            }
            consume(NT2 - 1);
            flushfn(gprev);
        }
    }
}

// =================== head (tiny, fp32) ===================
__global__ __launch_bounds__(256) void head_kernel(
    const unsigned int* __restrict__ pooled,
    const float* __restrict__ fc1_W, const float* __restrict__ fc1_b,
    const float* __restrict__ fc2_W, const float* __restrict__ fc2_b,
    const float* __restrict__ lab_W, const float* __restrict__ lab_b,
    const float* __restrict__ box_W, const float* __restrict__ box_b,
    float* __restrict__ out)
{
    __shared__ float p [GRAPHS][256];
    __shared__ float h1[GRAPHS][256];
    __shared__ float h2[GRAPHS][128];
    const int c = threadIdx.x;

    #pragma unroll
    for (int g = 0; g < GRAPHS; g++) {
        unsigned u = pooled[g*256 + c];
        u = (u & 0x80000000u) ? (u & 0x7fffffffu) : ~u;
        p[g][c] = __uint_as_float(u);
    }
    __syncthreads();

    float acc[GRAPHS];
    float bb = fc1_b[c];
    #pragma unroll
    for (int g = 0; g < GRAPHS; g++) acc[g] = bb;
    for (int k = 0; k < 256; k++) {
        float w = fc1_W[k*256 + c];
        #pragma unroll
        for (int g = 0; g < GRAPHS; g++) acc[g] += p[g][k] * w;
    }
    #pragma unroll
    for (int g = 0; g < GRAPHS; g++) h1[g][c] = fmaxf(acc[g], 0.0f);
    __syncthreads();

    if (c < 128) {
        float bb2 = fc2_b[c];
        #pragma unroll
        for (int g = 0; g < GRAPHS; g++) acc[g] = bb2;
        for (int k = 0; k < 256; k++) {
            float w = fc2_W[k*128 + c];
            #pragma unroll
            for (int g = 0; g < GRAPHS; g++) acc[g] += h1[g][k] * w;
        }
        #pragma unroll
        for (int g = 0; g < GRAPHS; g++) h2[g][c] = fmaxf(acc[g], 0.0f);
    }
    __syncthreads();

    if (c < 160) {
        int g = c / 10, j = c % 10;
        float a = lab_b[j];
        for (int k = 0; k < 128; k++) a += h2[g][k] * lab_W[k*10 + j];
        out[c] = a;
    } else {
        int t = c - 160;
        int g = t / 6, j = t % 6;
        float a = box_b[j];
        for (int k = 0; k < 128; k++) a += h2[g][k] * box_W[k*6 + j];
        out[160 + t] = a;
    }
}

extern "C" void kernel_launch(void* const* d_in, const int* in_sizes, int n_in,
                              void* d_out, int out_size, void* d_ws, size_t ws_size,
                              hipStream_t stream) {
    const float* pos   = (const float*)d_in[0];
    const int*   esrc  = (const int*)  d_in[1];
    const float* c1W1 = (const float*)d_in[4];
    const float* c1b1 = (const float*)d_in[5];
    const float* c1W2 = (const float*)d_in[6];
    const float* c1b2 = (const float*)d_in[7];
    const float* c2W1 = (const float*)d_in[8];
    const float* c2b1 = (const float*)d_in[9];
    const float* c2W2 = (const float*)d_in[10];
    const float* c2b2 = (const float*)d_in[11];
    const float* fc1W = (const float*)d_in[12];
    const float* fc1b = (const float*)d_in[13];
    const float* fc2W = (const float*)d_in[14];
    const float* fc2b = (const float*)d_in[15];
    const float* labW = (const float*)d_in[16];
    const float* labb = (const float*)d_in[17];
    const float* boxW = (const float*)d_in[18];
    const float* boxb = (const float*)d_in[19];

    __bf16* wsb = (__bf16*)d_ws;
    __bf16* x1  = wsb + OFF_X1;
    __bf16* p1  = wsb + OFF_P1;
    __bf16* p2  = wsb + OFF_P2;
    __bf16* p3  = wsb + OFF_P3;
    __bf16* p4  = wsb + OFF_P4;
    unsigned int* pooled = (unsigned int*)((char*)d_ws + OFF_POOL_BYTES);

    pack_weights<<<62, 256, 0, stream>>>(c1W1, c1W2, c2W1, c2W2, p1, p2, p3, p4, pooled);
    conv1_kernel<<<N_NODES / NB1, 256, 0, stream>>>(pos, esrc, p1, c1b1, p2, c1b2, x1);
    conv2_kernel<<<500, 512, 0, stream>>>(pos, esrc, x1, p3, c2b1, p4, c2b2, pooled);
    head_kernel<<<1, 256, 0, stream>>>(pooled, fc1W, fc1b, fc2W, fc2b,
                                       labW, labb, boxW, boxb, (float*)d_out);
}

// Round 6
// 268.997 us; speedup vs baseline: 1.8827x; 1.8827x over previous
//
#include <hip/hip_runtime.h>

#define N_NODES 20000
#define DEG 16
#define GRAPHS 16
#define NPG 1250

typedef __bf16 bf16x8 __attribute__((ext_vector_type(8)));
typedef float f32x4 __attribute__((ext_vector_type(4)));
#define MFMA16(a, b, c) __builtin_amdgcn_mfma_f32_16x16x32_bf16(a, b, c, 0, 0, 0)

// ---- workspace layout (bf16 element offsets) ----
#define OFF_X1    0            // x1 [20000][128] bf16
#define OFF_P1    2560000      // c1W1 packed: MT=8  KT=1 -> 4096
#define OFF_P2    2564096      // c1W2 packed: MT=8  KT=4 -> 16384
#define OFF_P3    2580480      // c2W1 packed: MT=16 KT=5 -> 40960
#define OFF_P4    2621440      // c2W2 packed: MT=16 KT=8 -> 65536
#define OFF_POOL_BYTES 5373952 // pooled u32[16*256]

// Frag layout (A-role == B-role for mfma_f32_16x16x32_bf16):
//   frag[((t*KT+kt)*64+lane)*8 + j] = X[k = kt*32 + (lane>>4)*8 + j][idx = lane&15]
__global__ __launch_bounds__(256) void pack_weights(
    const float* __restrict__ c1W1, const float* __restrict__ c1W2,
    const float* __restrict__ c2W1, const float* __restrict__ c2W2,
    __bf16* __restrict__ p1, __bf16* __restrict__ p2,
    __bf16* __restrict__ p3, __bf16* __restrict__ p4,
    unsigned int* __restrict__ pooled)
{
    int t = blockIdx.x * 256 + threadIdx.x;
    if (t < GRAPHS * 256) pooled[t] = 0u;   // flipped(-inf) == 0
    if (t >= 15872) return;
    const float* W; __bf16* out; int M, Kreal, KT, grp;
    if      (t <  512)  { W = c1W1; out = p1; M = 128; Kreal =   6; KT = 1; grp = t; }
    else if (t < 2560)  { W = c1W2; out = p2; M = 128; Kreal = 128; KT = 4; grp = t - 512; }
    else if (t < 7680)  { W = c2W1; out = p3; M = 256; Kreal = 131; KT = 5; grp = t - 2560; }
    else                { W = c2W2; out = p4; M = 256; Kreal = 256; KT = 8; grp = t - 7680; }
    int lane = grp & 63, rest = grp >> 6;
    int kt = rest % KT, mt = rest / KT;
    int m = mt * 16 + (lane & 15);
    int kbase = kt * 32 + ((lane >> 4) << 3);
    bf16x8 v;
    #pragma unroll
    for (int j = 0; j < 8; j++) {
        int k = kbase + j;
        v[j] = (k < Kreal) ? (__bf16)W[k * M + m] : (__bf16)0.f;
    }
    *(bf16x8*)&out[grp * 8] = v;
}

// =================== conv1 ===================
// 2500 blocks x 8 nodes, 4 blocks/CU. msg B-frags gathered straight to registers
// (quad-0 lanes carry k=0..5, rest zero). ONE barrier per block.
#define NB1 8
__global__ __launch_bounds__(256, 4) void conv1_kernel(
    const float* __restrict__ pos, const int* __restrict__ esrc,
    const __bf16* __restrict__ W1p, const float* __restrict__ b1,
    const __bf16* __restrict__ W2p, const float* __restrict__ b2,
    __bf16* __restrict__ x1)
{
    __shared__ __attribute__((aligned(16))) __bf16 hidF[NB1 * 4 * 64 * 8];  // 32 KB
    const int tid = threadIdx.x, lane = tid & 63, wave = tid >> 6;
    const int quad = lane >> 4, col = lane & 15;
    const int node0 = blockIdx.x * NB1;

    bf16x8 A1[2], B2w[2][4];
    f32x4 bias1[2];
    float b2v[2];
    #pragma unroll
    for (int i = 0; i < 2; i++) {
        int mtg = wave * 2 + i;
        A1[i] = *(const bf16x8*)&W1p[(mtg * 64 + lane) * 8];
        bias1[i] = *(const f32x4*)&b1[mtg * 16 + quad * 4];
        #pragma unroll
        for (int kt = 0; kt < 4; kt++)
            B2w[i][kt] = *(const bf16x8*)&W2p[((mtg * 4 + kt) * 64 + lane) * 8];
        b2v[i] = b2[mtg * 16 + col];
    }

    // ---- phase 1: gather msg to regs, MFMA, write hid frags ----
    #pragma unroll
    for (int nl = 0; nl < NB1; nl++) {
        bf16x8 B;
        #pragma unroll
        for (int j = 0; j < 8; j++) B[j] = (__bf16)0.f;
        if (quad == 0) {
            int d = node0 + nl;
            int s = esrc[d * 16 + col];
            float sx = pos[3*s], sy = pos[3*s+1], sz = pos[3*s+2];
            B[0] = (__bf16)sx; B[1] = (__bf16)sy; B[2] = (__bf16)sz;
            B[3] = (__bf16)(sx - pos[3*d]);
            B[4] = (__bf16)(sy - pos[3*d+1]);
            B[5] = (__bf16)(sz - pos[3*d+2]);
        }
        #pragma unroll
        for (int i = 0; i < 2; i++) {
            int mtg = wave * 2 + i;
            f32x4 acc = bias1[i];
            acc = MFMA16(A1[i], B, acc);
            union { __bf16 h[4]; uint2 u; } pk;
            #pragma unroll
            for (int r = 0; r < 4; r++) pk.h[r] = (__bf16)fmaxf(acc[r], 0.f);
            int kt2 = mtg >> 1;
            int lane2 = ((mtg * 2 + (quad >> 1)) & 3) * 16 + col;
            int j0 = (quad & 1) * 4;
            *(uint2*)&hidF[((nl * 4 + kt2) * 64 + lane2) * 8 + j0] = pk.u;
        }
    }
    __syncthreads();

    // ---- phase 2: D[edge][ch], edge-max, write x1 ----
    #pragma unroll
    for (int nl = 0; nl < NB1; nl++) {
        bf16x8 hA[4];
        #pragma unroll
        for (int kt = 0; kt < 4; kt++)
            hA[kt] = *(const bf16x8*)&hidF[((nl * 4 + kt) * 64 + lane) * 8];
        f32x4 acc[2];
        f32x4 z = {0.f, 0.f, 0.f, 0.f};
        acc[0] = z; acc[1] = z;
        #pragma unroll
        for (int kt = 0; kt < 4; kt++) {
            #pragma unroll
            for (int i = 0; i < 2; i++) acc[i] = MFMA16(hA[kt], B2w[i][kt], acc[i]);
        }
        #pragma unroll
        for (int i = 0; i < 2; i++) {
            int mtg = wave * 2 + i;
            float m = fmaxf(fmaxf(acc[i][0], acc[i][1]), fmaxf(acc[i][2], acc[i][3]));
            m = fmaxf(m, __shfl_xor(m, 16));
            m = fmaxf(m, __shfl_xor(m, 32));
            if (lane < 16)
                x1[(size_t)(node0 + nl) * 128 + mtg * 16 + lane] = (__bf16)(m + b2v[i]);
        }
    }
}

// =================== conv2 ===================
// 500 blocks x 512 threads x 40 nodes (20 tiles of NB2=2). launch_bounds(512,2)
// keeps VGPR ~100 (NO spill — R5's (512,4) spilled resident weights, 890MB HBM);
// at 100 VGPR + 52KB LDS the HW co-resides 2 blocks/CU = 4 waves/SIMD anyway.
// Producer waves 0-3: stage msg frags to LDS (shared x4), layer1 -> hidF.
// Consumer waves 4-7: W2 register-resident, layer2 + fused global max-pool.
#define NB2 2
#define NT2 20
__global__ __launch_bounds__(512, 2) void conv2_kernel(
    const float* __restrict__ pos, const int* __restrict__ esrc,
    const __bf16* __restrict__ x1,
    const __bf16* __restrict__ W1p, const float* __restrict__ b1,
    const __bf16* __restrict__ W2p, const float* __restrict__ b2,
    unsigned int* __restrict__ pooled)
{
    __shared__ __attribute__((aligned(16))) __bf16 msgF[2][NB2 * 5 * 64 * 8];  // 2x10 KB
    __shared__ __attribute__((aligned(16))) __bf16 hidF[2][NB2 * 8 * 64 * 8];  // 2x16 KB
    const int tid = threadIdx.x, lane = tid & 63, wave = tid >> 6;
    const int quad = lane >> 4, col = lane & 15;
    const int base = blockIdx.x * (NB2 * NT2);

    if (wave < 4) {
        // ===== producer: layer 1 =====
        bf16x8 A1[4][5];
        f32x4 bias1[4];
        #pragma unroll
        for (int i = 0; i < 4; i++) {
            int mtg = wave * 4 + i;
            #pragma unroll
            for (int kt = 0; kt < 5; kt++)
                A1[i][kt] = *(const bf16x8*)&W1p[((mtg * 5 + kt) * 64 + lane) * 8];
            bias1[i] = *(const f32x4*)&b1[mtg * 16 + quad * 4];
        }

        auto stage = [&](int n0, int buf) {
            #pragma unroll
            for (int s = 0; s < 3; s++) {
                int u = tid + 256 * s;
                if (u < NB2 * 5 * 64) {
                    int nl = u / 320, rr = u % 320;
                    int kt = rr >> 6, l = rr & 63;
                    int q = l >> 4, c = l & 15;
                    int d = n0 + nl;
                    if (kt < 4) {
                        int src = esrc[d * 16 + c];
                        *(uint4*)&msgF[buf][((nl * 5 + kt) * 64 + l) * 8] =
                            *(const uint4*)&x1[(size_t)src * 128 + kt * 32 + q * 8];
                    } else {
                        bf16x8 v;
                        #pragma unroll
                        for (int j = 0; j < 8; j++) v[j] = (__bf16)0.f;
                        if (q == 0) {
                            int src = esrc[d * 16 + c];
                            v[0] = (__bf16)(pos[3*src]   - pos[3*d]);
                            v[1] = (__bf16)(pos[3*src+1] - pos[3*d+1]);
                            v[2] = (__bf16)(pos[3*src+2] - pos[3*d+2]);
                        }
                        *(bf16x8*)&msgF[buf][((nl * 5 + kt) * 64 + l) * 8] = v;
                    }
                }
            }
        };

        stage(base, 0);
        __syncthreads();

        for (int k = 0; k < NT2; k++) {
            const int buf = k & 1;
            if (k + 1 < NT2) stage(base + (k + 1) * NB2, buf ^ 1);
            // compute layer1 for tile k from msgF[buf] -> hidF[buf]
            #pragma unroll
            for (int nl = 0; nl < NB2; nl++) {
                bf16x8 B[5];
                #pragma unroll
                for (int kt = 0; kt < 5; kt++)
                    B[kt] = *(const bf16x8*)&msgF[buf][((nl * 5 + kt) * 64 + lane) * 8];
                #pragma unroll
                for (int i = 0; i < 4; i++) {
                    int mtg = wave * 4 + i;
                    f32x4 acc = bias1[i];
                    #pragma unroll
                    for (int kt = 0; kt < 5; kt++) acc = MFMA16(A1[i][kt], B[kt], acc);
                    union { __bf16 h[4]; uint2 u; } pk;
                    #pragma unroll
                    for (int r = 0; r < 4; r++) pk.h[r] = (__bf16)fmaxf(acc[r], 0.f);
                    int kt2 = mtg >> 1;
                    int lane2 = ((mtg * 2 + (quad >> 1)) & 3) * 16 + col;
                    int j0 = (quad & 1) * 4;
                    *(uint2*)&hidF[buf][((nl * 8 + kt2) * 64 + lane2) * 8 + j0] = pk.u;
                }
            }
            __syncthreads();
        }
    } else {
        // ===== consumer: layer 2 + fused global max-pool =====
        const int wv = wave - 4;
        bf16x8 A2[4][8];
        #pragma unroll
        for (int i = 0; i < 4; i++) {
            int mtg = wv * 4 + i;
            #pragma unroll
            for (int kt = 0; kt < 8; kt++)
                A2[i][kt] = *(const bf16x8*)&W2p[((mtg * 8 + kt) * 64 + lane) * 8];
        }
        f32x4 runmax[4];
        #pragma unroll
        for (int i = 0; i < 4; i++)
            #pragma unroll
            for (int r = 0; r < 4; r++) runmax[i][r] = -3.4e38f;

        auto flushfn = [&](int g) {
            #pragma unroll
            for (int i = 0; i < 4; i++) {
                #pragma unroll
                for (int r = 0; r < 4; r++) {
                    float v = runmax[i][r];
                    v = fmaxf(v, __shfl_xor(v, 1));
                    v = fmaxf(v, __shfl_xor(v, 2));
                    v = fmaxf(v, __shfl_xor(v, 4));
                    v = fmaxf(v, __shfl_xor(v, 8));
                    if (col == 0) {
                        int c = (wv * 4 + i) * 16 + quad * 4 + r;
                        float val = v + b2[c];
                        unsigned u = __float_as_uint(val);
                        u = (u & 0x80000000u) ? ~u : (u | 0x80000000u);
                        atomicMax(&pooled[g * 256 + c], u);
                    }
                }
            }
        };
        auto consume = [&](int tk) {
            int buf1 = tk & 1;
            #pragma unroll
            for (int nl = 0; nl < NB2; nl++) {
                bf16x8 hB[8];
                #pragma unroll
                for (int kt = 0; kt < 8; kt++)
                    hB[kt] = *(const bf16x8*)&hidF[buf1][((nl * 8 + kt) * 64 + lane) * 8];
                f32x4 acc[4];
                f32x4 z = {0.f, 0.f, 0.f, 0.f};
                #pragma unroll
                for (int i = 0; i < 4; i++) acc[i] = z;
                #pragma unroll
                for (int kt = 0; kt < 8; kt++) {
                    #pragma unroll
                    for (int i = 0; i < 4; i++) acc[i] = MFMA16(A2[i][kt], hB[kt], acc[i]);
                }
                #pragma unroll
                for (int i = 0; i < 4; i++)
                    #pragma unroll
                    for (int r = 0; r < 4; r++)
                        runmax[i][r] = fmaxf(runmax[i][r], acc[i][r]);
            }
        };

        __syncthreads();   // matches producer's post-stage-0 barrier
        int gprev = base / NPG;
        for (int k = 0; k < NT2; k++) {
            if (k > 0) {
                int n0 = base + (k - 1) * NB2;
                int g = n0 / NPG;
                if (g != gprev) {
                    flushfn(gprev);
                    #pragma unroll
                    for (int i = 0; i < 4; i++)
                        #pragma unroll
                        for (int r = 0; r < 4; r++) runmax[i][r] = -3.4e38f;
                    gprev = g;
                }
                consume(k - 1);
            }
            __syncthreads();
        }
        {   // final tile
            int n0 = base + (NT2 - 1) * NB2;
            int g = n0 / NPG;
            if (g != gprev) {
                flushfn(gprev);
                #pragma unroll
                for (int i = 0; i < 4; i++)
                    #pragma unroll
                    for (int r = 0; r < 4; r++) runmax[i][r] = -3.4e38f;
                gprev = g;
            }
            consume(NT2 - 1);
            flushfn(gprev);
        }
    }
}

// =================== head (tiny, fp32) ===================
__global__ __launch_bounds__(256) void head_kernel(
    const unsigned int* __restrict__ pooled,
    const float* __restrict__ fc1_W, const float* __restrict__ fc1_b,
    const float* __restrict__ fc2_W, const float* __restrict__ fc2_b,
    const float* __restrict__ lab_W, const float* __restrict__ lab_b,
    const float* __restrict__ box_W, const float* __restrict__ box_b,
    float* __restrict__ out)
{
    __shared__ float p [GRAPHS][256];
    __shared__ float h1[GRAPHS][256];
    __shared__ float h2[GRAPHS][128];
    const int c = threadIdx.x;

    #pragma unroll
    for (int g = 0; g < GRAPHS; g++) {
        unsigned u = pooled[g*256 + c];
        u = (u & 0x80000000u) ? (u & 0x7fffffffu) : ~u;
        p[g][c] = __uint_as_float(u);
    }
    __syncthreads();

    float acc[GRAPHS];
    float bb = fc1_b[c];
    #pragma unroll
    for (int g = 0; g < GRAPHS; g++) acc[g] = bb;
    for (int k = 0; k < 256; k++) {
        float w = fc1_W[k*256 + c];
        #pragma unroll
        for (int g = 0; g < GRAPHS; g++) acc[g] += p[g][k] * w;
    }
    #pragma unroll
    for (int g = 0; g < GRAPHS; g++) h1[g][c] = fmaxf(acc[g], 0.0f);
    __syncthreads();

    if (c < 128) {
        float bb2 = fc2_b[c];
        #pragma unroll
        for (int g = 0; g < GRAPHS; g++) acc[g] = bb2;
        for (int k = 0; k < 256; k++) {
            float w = fc2_W[k*128 + c];
            #pragma unroll
            for (int g = 0; g < GRAPHS; g++) acc[g] += h1[g][k] * w;
        }
        #pragma unroll
        for (int g = 0; g < GRAPHS; g++) h2[g][c] = fmaxf(acc[g], 0.0f);
    }
    __syncthreads();

    if (c < 160) {
        int g = c / 10, j = c % 10;
        float a = lab_b[j];
        for (int k = 0; k < 128; k++) a += h2[g][k] * lab_W[k*10 + j];
        out[c] = a;
    } else {
        int t = c - 160;
        int g = t / 6, j = t % 6;
        float a = box_b[j];
        for (int k = 0; k < 128; k++) a += h2[g][k] * box_W[k*6 + j];
        out[160 + t] = a;
    }
}

extern "C" void kernel_launch(void* const* d_in, const int* in_sizes, int n_in,
                              void* d_out, int out_size, void* d_ws, size_t ws_size,
                              hipStream_t stream) {
    const float* pos   = (const float*)d_in[0];
    const int*   esrc  = (const int*)  d_in[1];
    const float* c1W1 = (const float*)d_in[4];
    const float* c1b1 = (const float*)d_in[5];
    const float* c1W2 = (const float*)d_in[6];
    const float* c1b2 = (const float*)d_in[7];
    const float* c2W1 = (const float*)d_in[8];
    const float* c2b1 = (const float*)d_in[9];
    const float* c2W2 = (const float*)d_in[10];
    const float* c2b2 = (const float*)d_in[11];
    const float* fc1W = (const float*)d_in[12];
    const float* fc1b = (const float*)d_in[13];
    const float* fc2W = (const float*)d_in[14];
    const float* fc2b = (const float*)d_in[15];
    const float* labW = (const float*)d_in[16];
    const float* labb = (const float*)d_in[17];
    const float* boxW = (const float*)d_in[18];
    const float* boxb = (const float*)d_in[19];

    __bf16* wsb = (__bf16*)d_ws;
    __bf16* x1  = wsb + OFF_X1;
    __bf16* p1  = wsb + OFF_P1;
    __bf16* p2  = wsb + OFF_P2;
    __bf16* p3  = wsb + OFF_P3;
    __bf16* p4  = wsb + OFF_P4;
    unsigned int* pooled = (unsigned int*)((char*)d_ws + OFF_POOL_BYTES);

    pack_weights<<<62, 256, 0, stream>>>(c1W1, c1W2, c2W1, c2W2, p1, p2, p3, p4, pooled);
    conv1_kernel<<<N_NODES / NB1, 256, 0, stream>>>(pos, esrc, p1, c1b1, p2, c1b2, x1);
    conv2_kernel<<<500, 512, 0, stream>>>(pos, esrc, x1, p3, c2b1, p4, c2b2, pooled);
    head_kernel<<<1, 256, 0, stream>>>(pooled, fc1W, fc1b, fc2W, fc2b,
                                       labW, labb, boxW, boxb, (float*)d_out);
}